// Round 13
// baseline (1243.384 us; speedup 1.0000x reference)
//
#include <hip/hip_runtime.h>
#include <hip/hip_bf16.h>

#define BB 8
#define NTOT 8
#define NREF 7
#define CC 128
#define HW 4096
#define QQ 1024
#define EPSV 1e-12f
#define NSPLIT 4
#define BNQ (BB * NREF * QQ)   // 57344

// d_out layout (f32 words):
//   out0 [0, 4194304)       : fused feature map (b,c,hw)
//   out1 [4194304, 4202496) : feat_indices (bf16-rounded f32)
//   out2 [4202496, 4259840) : ref_idx (exact ints until k_round quantizes)
#define OUT1_OFF ((size_t)BB * CC * HW)
#define OUT2_OFF (OUT1_OFF + (size_t)BB * QQ)

typedef __hip_bfloat16 bf16;

__device__ __forceinline__ float b2f(bf16 v) { return __bfloat162float(v); }
__device__ __forceinline__ float sane0(float x) {
    return (x == x && fabsf(x) < 60.f) ? x : 0.f;
}
// dtype-flag-aware load: element i of a logically-float tensor
__device__ __forceinline__ float ldv(const void* p, size_t i, int f32) {
    return f32 ? ((const float*)p)[i] : b2f(((const bf16*)p)[i]);
}
// quad load (elements i..i+3), dtype-aware
__device__ __forceinline__ float4 ldq(const void* p, size_t i, int f32) {
    if (f32) return *(const float4*)&((const float*)p)[i];
    ushort4 u = *(const ushort4*)&((const ushort*)p)[i];
    float4 v;
    v.x = b2f(*(const bf16*)&u.x); v.y = b2f(*(const bf16*)&u.y);
    v.z = b2f(*(const bf16*)&u.z); v.w = b2f(*(const bf16*)&u.w);
    return v;
}

// ---------------------------------------------------------------------------
// K0: detect per-tensor device dtype (f32 vs bf16). (Working since R8.)
__global__ void k_detect(const void* __restrict__ feat, const void* __restrict__ refs,
                         const void* __restrict__ sim, int* __restrict__ flags) {
    if (threadIdx.x == 0) {
        const ushort* p = (const ushort*)feat;
        int c1 = 0;
        for (int i = 0; i < 256; i++) {
            float v = b2f(*(const bf16*)&p[(size_t)i * 16384]);  // even idx
            if (!(fabsf(v) <= 100.f)) c1++;
        }
        flags[0] = c1 > 32 ? 1 : 0;
        p = (const ushort*)refs; c1 = 0;
        for (int i = 0; i < 256; i++) {
            float v = b2f(*(const bf16*)&p[(size_t)i * 131072]);
            if (!(fabsf(v) <= 100.f)) c1++;
        }
        flags[1] = c1 > 32 ? 1 : 0;
        p = (const ushort*)sim; c1 = 0;
        for (int i = 0; i < 32; i++) {
            float v = b2f(*(const bf16*)&p[i * 2]);
            if (!(fabsf(v) <= 100.f)) c1++;
        }
        flags[2] = c1 > 4 ? 1 : 0;
    }
}

// ---------------------------------------------------------------------------
// K1: per (b,q) selected feat column: l2norm over c twice -> wfs_t[b][c][q].
__global__ void k_wfs(const void* __restrict__ feat, const int* __restrict__ fidx,
                      const int* __restrict__ flags, float* __restrict__ wfs_t) {
    int ff = flags[0];
    int bq = blockIdx.x;
    int b = bq >> 10;
    int q = bq & 1023;
    int idx = fidx[b * QQ + q] & (HW - 1);
    int l = threadIdx.x;  // 0..63
    size_t base = (size_t)b * CC * HW + idx;
    float x0 = ldv(feat, base + (size_t)l * HW, ff);
    float x1 = ldv(feat, base + (size_t)(l + 64) * HW, ff);
    float s = x0 * x0 + x1 * x1;
    #pragma unroll
    for (int m = 1; m < 64; m <<= 1) s += __shfl_xor(s, m, 64);
    float d1 = fmaxf(sqrtf(s), EPSV);
    float y0 = x0 / d1, y1 = x1 / d1;
    float s2 = y0 * y0 + y1 * y1;
    #pragma unroll
    for (int m = 1; m < 64; m <<= 1) s2 += __shfl_xor(s2, m, 64);
    float d2 = fmaxf(sqrtf(s2), EPSV);
    wfs_t[((size_t)(b * CC + l)) * QQ + q] = y0 / d2;
    wfs_t[((size_t)(b * CC + l + 64)) * QQ + q] = y1 / d2;
}

// ---------------------------------------------------------------------------
// K2: rinv[b][n][k] = 1 / max(||refs[b,keep(n),:,k]||, eps)   (one IEEE div)
__global__ void k_rnorm(const void* __restrict__ refs, const int* __restrict__ pindex,
                        const int* __restrict__ flags, float* __restrict__ rinv) {
    int rf = flags[1];
    int gb = blockIdx.x;           // B*NREF*16
    int kc = gb & 15;
    int bn = gb >> 4;
    int n = bn % NREF;
    int b = bn / NREF;
    int index = *pindex & 7;
    int kn = n < index ? n : n + 1;
    int k = kc * 256 + threadIdx.x;
    size_t base = (size_t)(b * NTOT + kn) * CC * HW + k;
    float s = 0.f;
    #pragma unroll 4
    for (int c = 0; c < CC; c++) {
        float x = ldv(refs, base + (size_t)c * HW, rf);
        s = fmaf(x, x, s);
    }
    rinv[(b * NREF + n) * HW + k] = 1.0f / fmaxf(sqrtf(s), EPSV);
}

// ---------------------------------------------------------------------------
// K3 v6: R12 structure + register-prefetch software pipeline. Per c-chunk:
// barrier -> write prefetched regs to LDS -> barrier -> issue next chunk's
// global loads -> 2048 FMA (loads land under compute). Same summation order
// and values as R12 -> identical argmax.
__global__ __launch_bounds__(256, 3) void k_argmax(
        const void* __restrict__ refs, const float* __restrict__ wfs_t,
        const float* __restrict__ rinv, const int* __restrict__ pindex,
        const int* __restrict__ flags, float2* __restrict__ pairs) {
    __shared__ __align__(16) float lw[32][128];  // [c][q] 16 KiB
    __shared__ __align__(16) float lr[32][128];  // [c][k] 16 KiB
    int rf = flags[1];
    int gb = blockIdx.x;           // NSPLIT * 448
    int qtile = gb & 7;
    int r = gb >> 3;               // 0..NSPLIT*56-1
    int bn = r % 56;
    int ks = r / 56;
    int n = bn % NREF;
    int b = bn / NREF;
    int index = *pindex & 7;
    int kn = n < index ? n : n + 1;
    int q0 = qtile * 128;
    int kbase = ks * (HW / NSPLIT);
    int t = threadIdx.x;
    int qt = t >> 4, kt = t & 15;

    const float* wsrc = wfs_t + (size_t)b * CC * QQ + q0;
    size_t rbase = (size_t)(b * NTOT + kn) * CC * HW;
    const float* rib = rinv + (b * NREF + n) * HW;

    float best[8];
    int bidx[8];
    #pragma unroll
    for (int j = 0; j < 8; j++) { best[j] = -3.402823466e38f; bidx[j] = 0; }

    int x0 = (t & 31) * 4;    // staged k-quad within the 128-k tile
    int cb = t >> 5;          // 0..7

    float4 plw[4], plr[4];
    // prefetch g = 0 (ktile 0, chunk 0)
    #pragma unroll
    for (int i = 0; i < 4; i++) {
        int flat4 = i * 1024 + t * 4;
        int c = flat4 >> 7, x = flat4 & 127;
        plw[i] = *(const float4*)&wsrc[(size_t)c * QQ + x];
    }
    #pragma unroll
    for (int s = 0; s < 4; s++) {
        int c = cb + s * 8;
        plr[s] = ldq(refs, rbase + (size_t)c * HW + kbase + x0, rf);
    }

    for (int ktile = 0; ktile < 8; ktile++) {
        int k0 = kbase + ktile * 128;
        float4 ri4 = *(const float4*)&rib[k0 + x0];

        float acc[8][8];
        #pragma unroll
        for (int j = 0; j < 8; j++)
            #pragma unroll
            for (int i = 0; i < 8; i++) acc[j][i] = 0.f;

        for (int chunk = 0; chunk < 4; chunk++) {
            __syncthreads();  // previous chunk's LDS reads done
            // write prefetched registers to LDS (vmcnt wait already satisfied)
            #pragma unroll
            for (int i = 0; i < 4; i++) {
                int flat4 = i * 1024 + t * 4;
                int c = flat4 >> 7, x = flat4 & 127;
                *(float4*)&lw[c][x] = plw[i];
            }
            #pragma unroll
            for (int s = 0; s < 4; s++) {
                int c = cb + s * 8;
                float4 v = plr[s];
                v.x *= ri4.x; v.y *= ri4.y; v.z *= ri4.z; v.w *= ri4.w;
                *(float4*)&lr[c][x0] = v;
            }
            __syncthreads();

            // issue next chunk's global loads (land under the FMA block)
            int gn = ktile * 4 + chunk + 1;
            if (gn < 32) {
                int ktn = gn >> 2, chn = gn & 3;
                int cc0n = chn * 32;
                int k0n = kbase + ktn * 128;
                #pragma unroll
                for (int i = 0; i < 4; i++) {
                    int flat4 = i * 1024 + t * 4;
                    int c = flat4 >> 7, x = flat4 & 127;
                    plw[i] = *(const float4*)&wsrc[(size_t)(cc0n + c) * QQ + x];
                }
                #pragma unroll
                for (int s = 0; s < 4; s++) {
                    int c = cb + s * 8;
                    plr[s] = ldq(refs, rbase + (size_t)(cc0n + c) * HW + k0n + x0, rf);
                }
            }

            #pragma unroll 4
            for (int c = 0; c < 32; c++) {
                const float4 wq0 = *(const float4*)&lw[c][qt * 8];
                const float4 wq1 = *(const float4*)&lw[c][qt * 8 + 4];
                const float4 rk0 = *(const float4*)&lr[c][kt * 4];
                const float4 rk1 = *(const float4*)&lr[c][64 + kt * 4];
                const float wq[8] = {wq0.x, wq0.y, wq0.z, wq0.w,
                                     wq1.x, wq1.y, wq1.z, wq1.w};
                const float rk[8] = {rk0.x, rk0.y, rk0.z, rk0.w,
                                     rk1.x, rk1.y, rk1.z, rk1.w};
                #pragma unroll
                for (int j = 0; j < 8; j++)
                    #pragma unroll
                    for (int i = 0; i < 8; i++)
                        acc[j][i] = fmaf(wq[j], rk[i], acc[j][i]);
            }
        }

        // fold this tile (ascending k order preserved)
        #pragma unroll
        for (int j = 0; j < 8; j++) {
            #pragma unroll
            for (int i = 0; i < 8; i++) {
                float v = acc[j][i];
                int gk = k0 + (i < 4 ? kt * 4 + i : 64 + kt * 4 + (i - 4));
                if (v > best[j]) { best[j] = v; bidx[j] = gk; }
            }
        }
    }

    // reduce across the 16 kt-lanes (xor 1,2,4,8 stays in the 16-lane group)
    #pragma unroll
    for (int j = 0; j < 8; j++) {
        float v = best[j];
        int i = bidx[j];
        #pragma unroll
        for (int m = 1; m < 16; m <<= 1) {
            float vo = __shfl_xor(v, m, 64);
            int io = __shfl_xor(i, m, 64);
            if (vo > v || (vo == v && io < i)) { v = vo; i = io; }
        }
        if (kt == 0) {
            float2 pr; pr.x = v; pr.y = (float)i;
            pairs[(size_t)ks * BNQ + (size_t)(b * NREF + n) * QQ + q0 + qt * 8 + j] = pr;
        }
    }
}

// K3b: fold the NSPLIT partials (ascending split order keeps first-index ties)
__global__ void k_amax2(const float2* __restrict__ pairs, float* __restrict__ out2) {
    int j = blockIdx.x * 256 + threadIdx.x;  // 0..BNQ-1
    float2 best = pairs[j];
    #pragma unroll
    for (int s = 1; s < NSPLIT; s++) {
        float2 p = pairs[(size_t)s * BNQ + j];
        if (p.x > best.x) best = p;
    }
    out2[j] = best.y;
}

// ---------------------------------------------------------------------------
// K4a: out0 background = f32(feat), dtype-aware, scrubbed.
__global__ void k_cvt(const void* __restrict__ feat, const int* __restrict__ flags,
                      float* __restrict__ dst) {
    int ff = flags[0];
    size_t i4 = (size_t)blockIdx.x * 256 + threadIdx.x;
    float4 o;
    if (ff) {
        o = ((const float4*)feat)[i4];
    } else {
        ushort4 v = ((const ushort4*)feat)[i4];
        o.x = b2f(*(const bf16*)&v.x); o.y = b2f(*(const bf16*)&v.y);
        o.z = b2f(*(const bf16*)&v.z); o.w = b2f(*(const bf16*)&v.w);
    }
    o.x = sane0(o.x); o.y = sane0(o.y); o.z = sane0(o.z); o.w = sane0(o.w);
    ((float4*)dst)[i4] = o;
}

// K4b: output 1 (feat_indices, bf16-rounded f32)
__global__ void k_aux(const int* __restrict__ fidx, float* __restrict__ out) {
    int j = blockIdx.x * 256 + threadIdx.x;  // 0..8191
    float r = b2f(__float2bfloat16((float)fidx[j]));
    out[OUT1_OFF + j] = (r == r) ? r : 0.f;
}

// K4c: fused scatter at selected pixels (after k_cvt); reads exact out2.
__global__ void k_fuse(const void* __restrict__ feat, const void* __restrict__ refs,
                       const void* __restrict__ sim, const int* __restrict__ fidx,
                       const int* __restrict__ pindex, const int* __restrict__ flags,
                       float* __restrict__ out) {
    int ff = flags[0], rf = flags[1], sf = flags[2];
    int bq = blockIdx.x;
    int b = bq >> 10;
    int q = bq & 1023;
    int c = threadIdx.x;  // 0..127
    int index = *pindex & 7;
    int idx = fidx[b * QQ + q] & (HW - 1);
    float base = ldv(sim, b * NTOT + index, sf);
    float f = ldv(feat, ((size_t)(b * CC) + c) * HW + idx, ff);
    float s = 0.f;
    const float* ridxf = out + OUT2_OFF;
    #pragma unroll
    for (int n = 0; n < NREF; n++) {
        int kn = n < index ? n : n + 1;
        float sn = ldv(sim, b * NTOT + kn, sf);
        int rk = (int)ridxf[(size_t)(b * NREF + n) * QQ + q] & (HW - 1);
        float rv = ldv(refs, ((size_t)((b * NTOT + kn) * CC) + c) * HW + rk, rf);
        s = fmaf(sn, rv, s);
    }
    out[((size_t)(b * CC) + c) * HW + idx] = sane0(base * f + s);
}

// K4d: quantize out2 in place (bf16-rounded, matching the quantized reference)
__global__ void k_round(float* __restrict__ out) {
    int j = blockIdx.x * 256 + threadIdx.x;  // 0..57343
    float v = out[OUT2_OFF + j];
    float r = b2f(__float2bfloat16(v));
    out[OUT2_OFF + j] = (r == r && fabsf(r) < 1e6f) ? r : 0.f;
}

// ---------------------------------------------------------------------------
extern "C" void kernel_launch(void* const* d_in, const int* in_sizes, int n_in,
                              void* d_out, int out_size, void* d_ws, size_t ws_size,
                              hipStream_t stream) {
    // Bind pointers by size signature, not position.
    const void* feat = 0; const void* refs = 0; const void* sim = 0;
    const int* fidx = 0; const int* pindex = 0;
    for (int i = 0; i < n_in; i++) {
        switch (in_sizes[i]) {
            case BB * CC * HW:        feat = d_in[i]; break;               // 4194304
            case BB * NTOT * CC * HW: refs = d_in[i]; break;               // 33554432
            case BB * NTOT:           sim = d_in[i]; break;                // 64
            case BB * QQ:             fidx = (const int*)d_in[i]; break;   // 8192
            case 1:                   pindex = (const int*)d_in[i]; break;
        }
    }
    float* out = (float*)d_out;
    char* ws = (char*)d_ws;
    int* flags = (int*)ws;                                       // 16 B (pad 256)
    float* wfs_t = (float*)(ws + 256);                           // 4 MiB
    float* rinv = (float*)(ws + 256 + (size_t)BB * CC * QQ * 4);         // 896 KiB
    float2* pairs = (float2*)(ws + 256 + (size_t)BB * CC * QQ * 4
                                  + (size_t)BB * NREF * HW * 4);         // 1.75 MiB
    float* out2 = out + OUT2_OFF;

    k_detect<<<1, 64, 0, stream>>>(feat, refs, sim, flags);
    k_wfs<<<BB * QQ, 64, 0, stream>>>(feat, fidx, flags, wfs_t);
    k_rnorm<<<BB * NREF * (HW / 256), 256, 0, stream>>>(refs, pindex, flags, rinv);
    k_argmax<<<NSPLIT * BB * NREF * 8, 256, 0, stream>>>(refs, wfs_t, rinv, pindex, flags, pairs);
    k_amax2<<<BNQ / 256, 256, 0, stream>>>(pairs, out2);
    k_cvt<<<(BB * CC * HW / 4) / 256, 256, 0, stream>>>(feat, flags, out);
    k_aux<<<(BB * QQ) / 256, 256, 0, stream>>>(fidx, out);
    k_fuse<<<BB * QQ, 128, 0, stream>>>(feat, refs, sim, fidx, pindex, flags, out);
    k_round<<<(BB * NREF * QQ) / 256, 256, 0, stream>>>(out);
}

// Round 14
// 930.296 us; speedup vs baseline: 1.3365x; 1.3365x over previous
//
#include <hip/hip_runtime.h>
#include <hip/hip_bf16.h>

#define BB 8
#define NTOT 8
#define NREF 7
#define CC 128
#define HW 4096
#define QQ 1024
#define EPSV 1e-12f
#define NSPLIT 8
#define BNQ (BB * NREF * QQ)   // 57344

// d_out layout (f32 words):
//   out0 [0, 4194304)       : fused feature map (b,c,hw)
//   out1 [4194304, 4202496) : feat_indices (bf16-rounded f32)
//   out2 [4202496, 4259840) : ref_idx (exact ints until k_round quantizes)
// Transient scratch inside out0 (overwritten later by k_cvt):
//   pairs = out words [0, NSPLIT*BNQ*2) : per-split (best,idx) float2
#define OUT1_OFF ((size_t)BB * CC * HW)
#define OUT2_OFF (OUT1_OFF + (size_t)BB * QQ)

typedef __hip_bfloat16 bf16;

__device__ __forceinline__ float b2f(bf16 v) { return __bfloat162float(v); }
__device__ __forceinline__ float sane0(float x) {
    return (x == x && fabsf(x) < 60.f) ? x : 0.f;
}
// dtype-flag-aware load: element i of a logically-float tensor
__device__ __forceinline__ float ldv(const void* p, size_t i, int f32) {
    return f32 ? ((const float*)p)[i] : b2f(((const bf16*)p)[i]);
}

// ---------------------------------------------------------------------------
// K0: detect per-tensor device dtype (f32 vs bf16). (Working since R8.)
__global__ void k_detect(const void* __restrict__ feat, const void* __restrict__ refs,
                         const void* __restrict__ sim, int* __restrict__ flags) {
    if (threadIdx.x == 0) {
        const ushort* p = (const ushort*)feat;
        int c1 = 0;
        for (int i = 0; i < 256; i++) {
            float v = b2f(*(const bf16*)&p[(size_t)i * 16384]);  // even idx
            if (!(fabsf(v) <= 100.f)) c1++;
        }
        flags[0] = c1 > 32 ? 1 : 0;
        p = (const ushort*)refs; c1 = 0;
        for (int i = 0; i < 256; i++) {
            float v = b2f(*(const bf16*)&p[(size_t)i * 131072]);
            if (!(fabsf(v) <= 100.f)) c1++;
        }
        flags[1] = c1 > 32 ? 1 : 0;
        p = (const ushort*)sim; c1 = 0;
        for (int i = 0; i < 32; i++) {
            float v = b2f(*(const bf16*)&p[i * 2]);
            if (!(fabsf(v) <= 100.f)) c1++;
        }
        flags[2] = c1 > 4 ? 1 : 0;
    }
}

// ---------------------------------------------------------------------------
// K1: per (b,q) selected feat column: l2norm over c twice -> wfs_t[b][c][q].
__global__ void k_wfs(const void* __restrict__ feat, const int* __restrict__ fidx,
                      const int* __restrict__ flags, float* __restrict__ wfs_t) {
    int ff = flags[0];
    int bq = blockIdx.x;
    int b = bq >> 10;
    int q = bq & 1023;
    int idx = fidx[b * QQ + q] & (HW - 1);
    int l = threadIdx.x;  // 0..63
    size_t base = (size_t)b * CC * HW + idx;
    float x0 = ldv(feat, base + (size_t)l * HW, ff);
    float x1 = ldv(feat, base + (size_t)(l + 64) * HW, ff);
    float s = x0 * x0 + x1 * x1;
    #pragma unroll
    for (int m = 1; m < 64; m <<= 1) s += __shfl_xor(s, m, 64);
    float d1 = fmaxf(sqrtf(s), EPSV);
    float y0 = x0 / d1, y1 = x1 / d1;
    float s2 = y0 * y0 + y1 * y1;
    #pragma unroll
    for (int m = 1; m < 64; m <<= 1) s2 += __shfl_xor(s2, m, 64);
    float d2 = fmaxf(sqrtf(s2), EPSV);
    wfs_t[((size_t)(b * CC + l)) * QQ + q] = y0 / d2;
    wfs_t[((size_t)(b * CC + l + 64)) * QQ + q] = y1 / d2;
}

// ---------------------------------------------------------------------------
// K2: rinv[b][n][k] = 1 / max(||refs[b,keep(n),:,k]||, eps)   (one IEEE div)
__global__ void k_rnorm(const void* __restrict__ refs, const int* __restrict__ pindex,
                        const int* __restrict__ flags, float* __restrict__ rinv) {
    int rf = flags[1];
    int gb = blockIdx.x;           // B*NREF*16
    int kc = gb & 15;
    int bn = gb >> 4;
    int n = bn % NREF;
    int b = bn / NREF;
    int index = *pindex & 7;
    int kn = n < index ? n : n + 1;
    int k = kc * 256 + threadIdx.x;
    size_t base = (size_t)(b * NTOT + kn) * CC * HW + k;
    float s = 0.f;
    #pragma unroll 4
    for (int c = 0; c < CC; c++) {
        float x = ldv(refs, base + (size_t)c * HW, rf);
        s = fmaf(x, x, s);
    }
    rinv[(b * NREF + n) * HW + k] = 1.0f / fmaxf(sqrtf(s), EPSV);
}

// ---------------------------------------------------------------------------
// K3 (R12 structure, NSPLIT=8): 8q x 8k micro-tile, vector staging, rinv mul,
// no divides in the hot loop. Identical per-(q,k) arithmetic chain as R12.
__global__ __launch_bounds__(256, 4) void k_argmax(
        const void* __restrict__ refs, const float* __restrict__ wfs_t,
        const float* __restrict__ rinv, const int* __restrict__ pindex,
        const int* __restrict__ flags, float2* __restrict__ pairs) {
    __shared__ __align__(16) float lw[32][128];  // [c][q] 16 KiB
    __shared__ __align__(16) float lr[32][128];  // [c][k] 16 KiB
    int rf = flags[1];
    int gb = blockIdx.x;           // NSPLIT * 448
    int qtile = gb & 7;
    int r = gb >> 3;               // 0..NSPLIT*56-1
    int bn = r % 56;
    int ks = r / 56;
    int n = bn % NREF;
    int b = bn / NREF;
    int index = *pindex & 7;
    int kn = n < index ? n : n + 1;
    int q0 = qtile * 128;
    int kbase = ks * (HW / NSPLIT);
    int t = threadIdx.x;
    int qt = t >> 4, kt = t & 15;

    const float* wsrc = wfs_t + (size_t)b * CC * QQ + q0;
    size_t rbase = (size_t)(b * NTOT + kn) * CC * HW;
    const float* rib = rinv + (b * NREF + n) * HW;

    float best[8];
    int bidx[8];
    #pragma unroll
    for (int j = 0; j < 8; j++) { best[j] = -3.402823466e38f; bidx[j] = 0; }

    int x0 = (t & 31) * 4;    // staged k-quad within the 128-k tile
    int cb = t >> 5;          // 0..7

    for (int kt0 = 0; kt0 < HW / NSPLIT; kt0 += 128) {   // 4 k-tiles
        int k0 = kbase + kt0;
        float acc[8][8];
        #pragma unroll
        for (int j = 0; j < 8; j++)
            #pragma unroll
            for (int i = 0; i < 8; i++) acc[j][i] = 0.f;

        float4 ri4 = *(const float4*)&rib[k0 + x0];

        for (int cc0 = 0; cc0 < CC; cc0 += 32) {  // 4 c-chunks, ascending
            __syncthreads();  // previous phase's reads done
            // stage lw: 16 f32/thread, vectorized
            #pragma unroll
            for (int i = 0; i < 4; i++) {
                int flat4 = i * 1024 + t * 4;
                int c = flat4 >> 7, x = flat4 & 127;
                *(float4*)&lw[c][x] =
                    *(const float4*)&wsrc[(size_t)(cc0 + c) * QQ + x];
            }
            // stage lr: 4 k-quads x 4 c-rows per thread, scaled by rinv
            #pragma unroll
            for (int s = 0; s < 4; s++) {
                int c = cb + s * 8;      // 0..31
                float4 v;
                if (rf) {
                    v = *(const float4*)&((const float*)refs)
                            [rbase + (size_t)(cc0 + c) * HW + k0 + x0];
                } else {
                    ushort4 u = *(const ushort4*)&((const ushort*)refs)
                            [rbase + (size_t)(cc0 + c) * HW + k0 + x0];
                    v.x = b2f(*(const bf16*)&u.x); v.y = b2f(*(const bf16*)&u.y);
                    v.z = b2f(*(const bf16*)&u.z); v.w = b2f(*(const bf16*)&u.w);
                }
                v.x *= ri4.x; v.y *= ri4.y; v.z *= ri4.z; v.w *= ri4.w;
                *(float4*)&lr[c][x0] = v;
            }
            __syncthreads();

            #pragma unroll 4
            for (int c = 0; c < 32; c++) {
                const float4 wq0 = *(const float4*)&lw[c][qt * 8];
                const float4 wq1 = *(const float4*)&lw[c][qt * 8 + 4];
                const float4 rk0 = *(const float4*)&lr[c][kt * 4];
                const float4 rk1 = *(const float4*)&lr[c][64 + kt * 4];
                const float wq[8] = {wq0.x, wq0.y, wq0.z, wq0.w,
                                     wq1.x, wq1.y, wq1.z, wq1.w};
                const float rk[8] = {rk0.x, rk0.y, rk0.z, rk0.w,
                                     rk1.x, rk1.y, rk1.z, rk1.w};
                #pragma unroll
                for (int j = 0; j < 8; j++)
                    #pragma unroll
                    for (int i = 0; i < 8; i++)
                        acc[j][i] = fmaf(wq[j], rk[i], acc[j][i]);
            }
        }

        // fold this tile (ascending k order preserved)
        #pragma unroll
        for (int j = 0; j < 8; j++) {
            #pragma unroll
            for (int i = 0; i < 8; i++) {
                float v = acc[j][i];
                int gk = k0 + (i < 4 ? kt * 4 + i : 64 + kt * 4 + (i - 4));
                if (v > best[j]) { best[j] = v; bidx[j] = gk; }
            }
        }
    }

    // reduce across the 16 kt-lanes (xor 1,2,4,8 stays in the 16-lane group)
    #pragma unroll
    for (int j = 0; j < 8; j++) {
        float v = best[j];
        int i = bidx[j];
        #pragma unroll
        for (int m = 1; m < 16; m <<= 1) {
            float vo = __shfl_xor(v, m, 64);
            int io = __shfl_xor(i, m, 64);
            if (vo > v || (vo == v && io < i)) { v = vo; i = io; }
        }
        if (kt == 0) {
            float2 pr; pr.x = v; pr.y = (float)i;
            pairs[(size_t)ks * BNQ + (size_t)(b * NREF + n) * QQ + q0 + qt * 8 + j] = pr;
        }
    }
}

// K3b: fold the NSPLIT partials (ascending split order keeps first-index ties)
__global__ void k_amax2(const float2* __restrict__ pairs, float* __restrict__ out2) {
    int j = blockIdx.x * 256 + threadIdx.x;  // 0..BNQ-1
    float2 best = pairs[j];
    #pragma unroll
    for (int s = 1; s < NSPLIT; s++) {
        float2 p = pairs[(size_t)s * BNQ + j];
        if (p.x > best.x) best = p;
    }
    out2[j] = best.y;
}

// ---------------------------------------------------------------------------
// K4a: out0 background = f32(feat), dtype-aware, scrubbed. Runs AFTER k_amax2
// (overwrites the pairs scratch living at the start of out0).
__global__ void k_cvt(const void* __restrict__ feat, const int* __restrict__ flags,
                      float* __restrict__ dst) {
    int ff = flags[0];
    size_t i4 = (size_t)blockIdx.x * 256 + threadIdx.x;
    float4 o;
    if (ff) {
        o = ((const float4*)feat)[i4];
    } else {
        ushort4 v = ((const ushort4*)feat)[i4];
        o.x = b2f(*(const bf16*)&v.x); o.y = b2f(*(const bf16*)&v.y);
        o.z = b2f(*(const bf16*)&v.z); o.w = b2f(*(const bf16*)&v.w);
    }
    o.x = sane0(o.x); o.y = sane0(o.y); o.z = sane0(o.z); o.w = sane0(o.w);
    ((float4*)dst)[i4] = o;
}

// K4b: output 1 (feat_indices, bf16-rounded f32)
__global__ void k_aux(const int* __restrict__ fidx, float* __restrict__ out) {
    int j = blockIdx.x * 256 + threadIdx.x;  // 0..8191
    float r = b2f(__float2bfloat16((float)fidx[j]));
    out[OUT1_OFF + j] = (r == r) ? r : 0.f;
}

// K4c: fused scatter at selected pixels (after k_cvt); reads exact out2.
__global__ void k_fuse(const void* __restrict__ feat, const void* __restrict__ refs,
                       const void* __restrict__ sim, const int* __restrict__ fidx,
                       const int* __restrict__ pindex, const int* __restrict__ flags,
                       float* __restrict__ out) {
    int ff = flags[0], rf = flags[1], sf = flags[2];
    int bq = blockIdx.x;
    int b = bq >> 10;
    int q = bq & 1023;
    int c = threadIdx.x;  // 0..127
    int index = *pindex & 7;
    int idx = fidx[b * QQ + q] & (HW - 1);
    float base = ldv(sim, b * NTOT + index, sf);
    float f = ldv(feat, ((size_t)(b * CC) + c) * HW + idx, ff);
    float s = 0.f;
    const float* ridxf = out + OUT2_OFF;
    #pragma unroll
    for (int n = 0; n < NREF; n++) {
        int kn = n < index ? n : n + 1;
        float sn = ldv(sim, b * NTOT + kn, sf);
        int rk = (int)ridxf[(size_t)(b * NREF + n) * QQ + q] & (HW - 1);
        float rv = ldv(refs, ((size_t)((b * NTOT + kn) * CC) + c) * HW + rk, rf);
        s = fmaf(sn, rv, s);
    }
    out[((size_t)(b * CC) + c) * HW + idx] = sane0(base * f + s);
}

// K4d: quantize out2 in place (bf16-rounded, matching the quantized reference)
__global__ void k_round(float* __restrict__ out) {
    int j = blockIdx.x * 256 + threadIdx.x;  // 0..57343
    float v = out[OUT2_OFF + j];
    float r = b2f(__float2bfloat16(v));
    out[OUT2_OFF + j] = (r == r && fabsf(r) < 1e6f) ? r : 0.f;
}

// ---------------------------------------------------------------------------
extern "C" void kernel_launch(void* const* d_in, const int* in_sizes, int n_in,
                              void* d_out, int out_size, void* d_ws, size_t ws_size,
                              hipStream_t stream) {
    // Bind pointers by size signature, not position.
    const void* feat = 0; const void* refs = 0; const void* sim = 0;
    const int* fidx = 0; const int* pindex = 0;
    for (int i = 0; i < n_in; i++) {
        switch (in_sizes[i]) {
            case BB * CC * HW:        feat = d_in[i]; break;               // 4194304
            case BB * NTOT * CC * HW: refs = d_in[i]; break;               // 33554432
            case BB * NTOT:           sim = d_in[i]; break;                // 64
            case BB * QQ:             fidx = (const int*)d_in[i]; break;   // 8192
            case 1:                   pindex = (const int*)d_in[i]; break;
        }
    }
    float* out = (float*)d_out;
    char* ws = (char*)d_ws;
    int* flags = (int*)ws;                                       // 16 B (pad 256)
    float* wfs_t = (float*)(ws + 256);                           // 4 MiB
    float* rinv = (float*)(ws + 256 + (size_t)BB * CC * QQ * 4);         // 896 KiB
    // pairs scratch lives at the start of out0 (overwritten later by k_cvt)
    float2* pairs = (float2*)out;                                // 3.5 MiB
    float* out2 = out + OUT2_OFF;

    k_detect<<<1, 64, 0, stream>>>(feat, refs, sim, flags);
    k_wfs<<<BB * QQ, 64, 0, stream>>>(feat, fidx, flags, wfs_t);
    k_rnorm<<<BB * NREF * (HW / 256), 256, 0, stream>>>(refs, pindex, flags, rinv);
    k_argmax<<<NSPLIT * BB * NREF * 8, 256, 0, stream>>>(refs, wfs_t, rinv, pindex, flags, pairs);
    k_amax2<<<BNQ / 256, 256, 0, stream>>>(pairs, out2);
    k_cvt<<<(BB * CC * HW / 4) / 256, 256, 0, stream>>>(feat, flags, out);
    k_aux<<<(BB * QQ) / 256, 256, 0, stream>>>(fidx, out);
    k_fuse<<<BB * QQ, 128, 0, stream>>>(feat, refs, sim, fidx, pindex, flags, out);
    k_round<<<(BB * NREF * QQ) / 256, 256, 0, stream>>>(out);
}